// Round 15
// baseline (652.611 us; speedup 1.0000x reference)
//
#include <hip/hip_runtime.h>
#include <math.h>

#define BATCH 2
#define SEQ 2048
#define DM 1024
#define NH 16
#define DH 64
#define TOPKN 1024
#define MROWS (BATCH * SEQ)  // 4096

typedef float f32x4 __attribute__((ext_vector_type(4)));
typedef short s16x8 __attribute__((ext_vector_type(8)));
typedef short s16x4 __attribute__((ext_vector_type(4)));

// PV MFMA: 16x16x16 bf16 (B-fragment k-chunk of 4 matches swapped-QK^T acc layout)
#if __has_builtin(__builtin_amdgcn_mfma_f32_16x16x16_bf16)
#define MFMA1616(acc, a, b) acc = __builtin_amdgcn_mfma_f32_16x16x16_bf16(a, b, acc, 0, 0, 0)
#define MFMA1616_FENCE()
#elif __has_builtin(__builtin_amdgcn_mfma_f32_16x16x16bf16_1k)
#define MFMA1616(acc, a, b) acc = __builtin_amdgcn_mfma_f32_16x16x16bf16_1k(a, b, acc, 0, 0, 0)
#define MFMA1616_FENCE()
#else
#define MFMA1616(acc, a, b) \
  asm volatile("v_mfma_f32_16x16x16_bf16 %0, %1, %2, %0" : "+v"(acc) : "v"(a), "v"(b))
#define MFMA1616_FENCE() asm volatile("s_nop 7\ns_nop 7")
#endif

__device__ __forceinline__ unsigned short f2bf(float x) {
  unsigned u = __float_as_uint(x);
  return (unsigned short)((u + 0x7FFFu + ((u >> 16) & 1u)) >> 16);
}
__device__ __forceinline__ unsigned packHL(float x) {
  unsigned h = f2bf(x);
  float r = x - __uint_as_float(h << 16);
  unsigned l = f2bf(r);
  return h | (l << 16);
}
// hi-bf16 pair of two f32 (truncated) -> one u32 via v_perm
__device__ __forceinline__ unsigned hipair(float a, float b) {
  return __builtin_amdgcn_perm(__float_as_uint(b), __float_as_uint(a), 0x07060302u);
}
// lo-residual bf16 pair (RNE) via v_cvt_pk_bf16_f32
__device__ __forceinline__ unsigned lopair(float a, float b) {
  float ra = a - __uint_as_float(__float_as_uint(a) & 0xFFFF0000u);
  float rb = b - __uint_as_float(__float_as_uint(b) & 0xFFFF0000u);
  unsigned out;
  asm("v_cvt_pk_bf16_f32 %0, %1, %2" : "=v"(out) : "v"(ra), "v"(rb));
  return out;
}

// ---------------- W pre-convert: f32 -> hi/lo bf16 slabs ----------------
__global__ __launch_bounds__(256) void convW(const float* __restrict__ W,
                                             unsigned short* __restrict__ Whi,
                                             unsigned short* __restrict__ Wlo) {
  int i = (blockIdx.x * 256 + threadIdx.x) * 4;
  float4 x = *(const float4*)&W[i];
  float xs[4] = {x.x, x.y, x.z, x.w};
  union { s16x4 v; unsigned short s[4]; } hu, lu;
#pragma unroll
  for (int e = 0; e < 4; ++e) {
    unsigned short hb = f2bf(xs[e]);
    hu.s[e] = hb;
    lu.s[e] = f2bf(xs[e] - __uint_as_float((unsigned)hb << 16));
  }
  *(s16x4*)&Whi[i] = hu.v;
  *(s16x4*)&Wlo[i] = lu.v;
}

// ---------------- MFMA GEMM: C[4096,1024] = A @ W^T + bias ----------------
// 3-term split-bf16. BM=128, BN=128, BK=64; 512 thr (8 waves 2x4), wave-tile 64x32.
// ASRC: 0 = f32 A (truncate-hi), 1 = packed u32 (hi|lo<<16).
// MODE: 0 f32 out, 1 packed Q(*1024 == 8192/8), 2 Khi/Klo, 3 Vt transposed.
template <int ASRC, int MODE>
__global__ __launch_bounds__(512) void gemm_mfma(
    const void* __restrict__ Asrc, const unsigned short* __restrict__ Whi,
    const unsigned short* __restrict__ Wlo, const float* __restrict__ bias,
    void* __restrict__ out0, void* __restrict__ out1) {
  __shared__ unsigned short Ah[128][64], Al[128][64];
  __shared__ unsigned short Bh[128][64], Bl[128][64];

  const int f = blockIdx.x;              // 256 blocks
  const int xcd = f & 7, r_ = f >> 3;
  const int bm = xcd * 4 + (r_ >> 3);
  const int bn = r_ & 7;
  const int m0g = bm * 128, n0g = bn * 128;
  const int t = threadIdx.x, w = t >> 6, lane = t & 63;
  const int g = lane >> 4, c = lane & 15;
  const int wm = w >> 2, wn = w & 3;

  f32x4 acc[4][2];
#pragma unroll
  for (int i = 0; i < 4; ++i)
#pragma unroll
    for (int j = 0; j < 2; ++j) acc[i][j] = (f32x4){0.f, 0.f, 0.f, 0.f};

#pragma unroll 1
  for (int k0 = 0; k0 < 1024; k0 += 64) {
#pragma unroll
    for (int i = 0; i < 2; ++i) {
      int oid = t * 2 + i;
      int rr = oid >> 3, j = oid & 7;
      unsigned hw[4], lw[4];
      if (ASRC == 0) {
        const float* src = (const float*)Asrc + (size_t)(m0g + rr) * 1024 + k0 + j * 8;
        float4 x0 = *(const float4*)src, x1 = *(const float4*)(src + 4);
        float xs[8] = {x0.x, x0.y, x0.z, x0.w, x1.x, x1.y, x1.z, x1.w};
#pragma unroll
        for (int p = 0; p < 4; ++p) {
          hw[p] = hipair(xs[2 * p], xs[2 * p + 1]);
          lw[p] = lopair(xs[2 * p], xs[2 * p + 1]);
        }
      } else {
        const unsigned* src = (const unsigned*)Asrc + (size_t)(m0g + rr) * 1024 + k0 + j * 8;
        uint4 u0 = *(const uint4*)src, u1 = *(const uint4*)(src + 4);
        unsigned us[8] = {u0.x, u0.y, u0.z, u0.w, u1.x, u1.y, u1.z, u1.w};
#pragma unroll
        for (int p = 0; p < 4; ++p) {
          hw[p] = __builtin_amdgcn_perm(us[2 * p + 1], us[2 * p], 0x05040100u);
          lw[p] = __builtin_amdgcn_perm(us[2 * p + 1], us[2 * p], 0x07060302u);
        }
      }
      int od = (j ^ (rr & 7)) * 8;
      *(uint4*)&Ah[rr][od] = make_uint4(hw[0], hw[1], hw[2], hw[3]);
      *(uint4*)&Al[rr][od] = make_uint4(lw[0], lw[1], lw[2], lw[3]);
    }
#pragma unroll
    for (int i = 0; i < 4; ++i) {
      int oid = t * 4 + i;
      int pl = oid >> 10, idx = oid & 1023, rr = idx >> 3, j = idx & 7;
      const unsigned short* src = (pl ? Wlo : Whi) + (size_t)(n0g + rr) * 1024 + k0 + j * 8;
      uint4 d = *(const uint4*)src;
      int od = (j ^ (rr & 7)) * 8;
      if (pl) *(uint4*)&Bl[rr][od] = d; else *(uint4*)&Bh[rr][od] = d;
    }
    __syncthreads();
#pragma unroll
    for (int k2 = 0; k2 < 2; ++k2) {
      s16x8 ah[4], al4[4], bh[2], bl[2];
      int ob = ((k2 * 4 + g) ^ (c & 7)) * 8;
#pragma unroll
      for (int i = 0; i < 4; ++i) {
        int rr = wm * 64 + i * 16 + c;
        ah[i] = *(const s16x8*)&Ah[rr][ob];
        al4[i] = *(const s16x8*)&Al[rr][ob];
      }
#pragma unroll
      for (int j = 0; j < 2; ++j) {
        int rr = wn * 32 + j * 16 + c;
        bh[j] = *(const s16x8*)&Bh[rr][ob];
        bl[j] = *(const s16x8*)&Bl[rr][ob];
      }
#pragma unroll
      for (int i = 0; i < 4; ++i)
#pragma unroll
        for (int j = 0; j < 2; ++j) {
          acc[i][j] = __builtin_amdgcn_mfma_f32_16x16x32_bf16(ah[i], bh[j], acc[i][j], 0, 0, 0);
          acc[i][j] = __builtin_amdgcn_mfma_f32_16x16x32_bf16(ah[i], bl[j], acc[i][j], 0, 0, 0);
          acc[i][j] = __builtin_amdgcn_mfma_f32_16x16x32_bf16(al4[i], bh[j], acc[i][j], 0, 0, 0);
        }
    }
    __syncthreads();
  }

#pragma unroll
  for (int j = 0; j < 2; ++j) {
    const int col = n0g + wn * 32 + j * 16 + c;
    const float bj = bias[col];
#pragma unroll
    for (int i = 0; i < 4; ++i) {
      const int row0 = m0g + wm * 64 + i * 16 + g * 4;
      if (MODE == 0) {
        float* O = (float*)out0;
#pragma unroll
        for (int rr = 0; rr < 4; ++rr)
          O[(size_t)(row0 + rr) * 1024 + col] = acc[i][j][rr] + bj;
      } else if (MODE == 1) {
        unsigned* Q = (unsigned*)out0;
#pragma unroll
        for (int rr = 0; rr < 4; ++rr)
          Q[(size_t)(row0 + rr) * 1024 + col] = packHL((acc[i][j][rr] + bj) * 1024.0f);
      } else if (MODE == 2) {
        unsigned short* Khi = (unsigned short*)out0;
        unsigned short* Klo = (unsigned short*)out1;
#pragma unroll
        for (int rr = 0; rr < 4; ++rr) {
          float x = acc[i][j][rr] + bj;
          unsigned short hb = f2bf(x);
          Khi[(size_t)(row0 + rr) * 1024 + col] = hb;
          Klo[(size_t)(row0 + rr) * 1024 + col] = f2bf(x - __uint_as_float((unsigned)hb << 16));
        }
      } else {
        unsigned short* Vt = (unsigned short*)out0;
        int b = row0 >> 11, l0 = row0 & (SEQ - 1);
        int h = col >> 6, dh = col & 63;
        union { s16x4 v; unsigned short sh[4]; } vv;
#pragma unroll
        for (int rr = 0; rr < 4; ++rr) vv.sh[rr] = f2bf(acc[i][j][rr] + bj);
        *(s16x4*)&Vt[(((size_t)b * NH + h) * DH + dh) * SEQ + l0] = vv.v;
      }
    }
  }
}

// ---------------- fused prob-sparse attention (q=32, pipelined loads) ---------
// 2048 WGs x 1024 thr (16 waves). 32 q-rows per WG, k-split 16 x 128.
// Q pre-scaled by 1024 -> MFMA with acc INIT=32768.5 yields the u16 code
// u = s*8192 + 32768.5 directly (quantize = fmin + cvt, no fmaf).
// K loads explicitly double-buffered (slot = tt&1 in fully unrolled loop);
// same for V in PV. Bisection uses round-13's explicit compares (the
// round-14 packed-u16 builtins scalarized and regressed).
__global__ __launch_bounds__(1024, 4) void attn_mfma(
    const unsigned* __restrict__ QHL, const unsigned short* __restrict__ Khi,
    const unsigned short* __restrict__ Klo, const unsigned short* __restrict__ Vt,
    unsigned* __restrict__ CtxP) {
  __shared__ __align__(16) char smem[16 * 32 * 66 * 4];
  __shared__ __align__(16) float szum[32][16];
  __shared__ unsigned Tlds[32];
  unsigned (*sc)[1028] = (unsigned(*)[1028])smem;
  float (*ctxp)[32][66] = (float(*)[32][66])smem;

  int wg = blockIdx.x;
  wg = (wg & 7) * 256 + (wg >> 3);                  // XCD-contiguous (2048 = 8*256)
  const int bh = wg >> 6, qt = wg & 63;
  const int b = bh >> 4, h = bh & 15;
  const int q0 = qt * 32;
  const int t = threadIdx.x, wid = t >> 6, lane = t & 63;
  const int g = lane >> 4, c = lane & 15;
  const size_t rowb = (size_t)b * SEQ;

  // ---- Q B-fragments for both q-halves (packed u32, pre-scaled by 1024) ----
  s16x8 qhiA[2], qloA[2], qhiB[2], qloB[2];
#pragma unroll
  for (int qh = 0; qh < 2; ++qh) {
    const unsigned* qp = QHL + (rowb + q0 + qh * 16 + c) * DM + h * DH + g * 8;
#pragma unroll
    for (int ds = 0; ds < 2; ++ds) {
      unsigned uw[8];
      *(uint4*)&uw[0] = *(const uint4*)(qp + ds * 32);
      *(uint4*)&uw[4] = *(const uint4*)(qp + ds * 32 + 4);
      union { s16x8 v; unsigned u[4]; } hi_, lo_;
#pragma unroll
      for (int p = 0; p < 4; ++p) {
        hi_.u[p] = (uw[2 * p] & 0xFFFFu) | (uw[2 * p + 1] << 16);
        lo_.u[p] = (uw[2 * p] >> 16) | (uw[2 * p + 1] & 0xFFFF0000u);
      }
      if (qh == 0) { qhiA[ds] = hi_.v; qloA[ds] = lo_.v; }
      else         { qhiB[ds] = hi_.v; qloB[ds] = lo_.v; }
    }
  }

  // ---- swapped QK^T with 2-stage K prefetch -> u16 codes ----
  unsigned pkA[8][2], pkB[8][2];
  {
    const f32x4 INIT = (f32x4){32768.5f, 32768.5f, 32768.5f, 32768.5f};
    const size_t kcol = (size_t)h * DH + g * 8;
    const size_t kbase = (rowb + wid * 128 + c) * DM + kcol;
    s16x8 kh0[2], kh1[2], kl0[2], kl1[2];
    // preload tt=0 into slot 0
    kh0[0] = *(const s16x8*)(Khi + kbase);
    kh1[0] = *(const s16x8*)(Khi + kbase + 32);
    kl0[0] = *(const s16x8*)(Klo + kbase);
    kl1[0] = *(const s16x8*)(Klo + kbase + 32);
#pragma unroll
    for (int tt = 0; tt < 8; ++tt) {
      const int cur = tt & 1, nxt = cur ^ 1;
      if (tt < 7) {
        const size_t krow = kbase + (size_t)(tt + 1) * 16 * DM;
        kh0[nxt] = *(const s16x8*)(Khi + krow);
        kh1[nxt] = *(const s16x8*)(Khi + krow + 32);
        kl0[nxt] = *(const s16x8*)(Klo + krow);
        kl1[nxt] = *(const s16x8*)(Klo + krow + 32);
      }
      f32x4 aA = __builtin_amdgcn_mfma_f32_16x16x32_bf16(kh0[cur], qhiA[0], INIT, 0, 0, 0);
      f32x4 aB = __builtin_amdgcn_mfma_f32_16x16x32_bf16(kh0[cur], qhiB[0], INIT, 0, 0, 0);
      aA = __builtin_amdgcn_mfma_f32_16x16x32_bf16(kh1[cur], qhiA[1], aA, 0, 0, 0);
      aB = __builtin_amdgcn_mfma_f32_16x16x32_bf16(kh1[cur], qhiB[1], aB, 0, 0, 0);
      aA = __builtin_amdgcn_mfma_f32_16x16x32_bf16(kl0[cur], qhiA[0], aA, 0, 0, 0);
      aB = __builtin_amdgcn_mfma_f32_16x16x32_bf16(kl0[cur], qhiB[0], aB, 0, 0, 0);
      aA = __builtin_amdgcn_mfma_f32_16x16x32_bf16(kl1[cur], qhiA[1], aA, 0, 0, 0);
      aB = __builtin_amdgcn_mfma_f32_16x16x32_bf16(kl1[cur], qhiB[1], aB, 0, 0, 0);
      aA = __builtin_amdgcn_mfma_f32_16x16x32_bf16(kh0[cur], qloA[0], aA, 0, 0, 0);
      aB = __builtin_amdgcn_mfma_f32_16x16x32_bf16(kh0[cur], qloB[0], aB, 0, 0, 0);
      aA = __builtin_amdgcn_mfma_f32_16x16x32_bf16(kh1[cur], qloA[1], aA, 0, 0, 0);
      aB = __builtin_amdgcn_mfma_f32_16x16x32_bf16(kh1[cur], qloB[1], aB, 0, 0, 0);
      unsigned a0 = (unsigned)fminf(aA[0], 65535.f);
      unsigned a1 = (unsigned)fminf(aA[1], 65535.f);
      unsigned a2 = (unsigned)fminf(aA[2], 65535.f);
      unsigned a3 = (unsigned)fminf(aA[3], 65535.f);
      pkA[tt][0] = a0 | (a1 << 16);
      pkA[tt][1] = a2 | (a3 << 16);
      unsigned b0 = (unsigned)fminf(aB[0], 65535.f);
      unsigned b1 = (unsigned)fminf(aB[1], 65535.f);
      unsigned b2 = (unsigned)fminf(aB[2], 65535.f);
      unsigned b3 = (unsigned)fminf(aB[3], 65535.f);
      pkB[tt][0] = b0 | (b1 << 16);
      pkB[tt][1] = b2 | (b3 << 16);
    }
  }

  // ---- S1: publish score tile ----
#pragma unroll
  for (int tt = 0; tt < 8; ++tt) {
    int col = wid * 64 + tt * 8 + g * 2;
    *(uint2*)&sc[c][col] = make_uint2(pkA[tt][0], pkA[tt][1]);
    *(uint2*)&sc[c + 16][col] = make_uint2(pkB[tt][0], pkB[tt][1]);
  }
  __syncthreads();

  // ---- S2: wave-local exact selection (explicit compares, round-13 form) ----
  {
    const int r = 2 * wid + (lane >> 5);
    const int hl = lane & 31;
    uint4 ts[8];
#pragma unroll
    for (int i = 0; i < 8; ++i)
      ts[i] = *(const uint4*)&sc[r][hl * 4 + i * 128];

    unsigned lo = 30720u, hi = 34816u;
#pragma unroll 1
    for (int it = 0; it < 12; ++it) {
      const unsigned mid = (lo + hi) >> 1;
      int cnt = 0;
#pragma unroll
      for (int i = 0; i < 8; ++i) {
        unsigned a0 = ts[i].x, a1 = ts[i].y, a2 = ts[i].z, a3 = ts[i].w;
        cnt += ((a0 & 0xFFFFu) >= mid) ? 1 : 0;
        cnt += ((a0 >> 16) >= mid) ? 1 : 0;
        cnt += ((a1 & 0xFFFFu) >= mid) ? 1 : 0;
        cnt += ((a1 >> 16) >= mid) ? 1 : 0;
        cnt += ((a2 & 0xFFFFu) >= mid) ? 1 : 0;
        cnt += ((a2 >> 16) >= mid) ? 1 : 0;
        cnt += ((a3 & 0xFFFFu) >= mid) ? 1 : 0;
        cnt += ((a3 >> 16) >= mid) ? 1 : 0;
      }
      cnt += __shfl_xor(cnt, 1);
      cnt += __shfl_xor(cnt, 2);
      cnt += __shfl_xor(cnt, 4);
      cnt += __shfl_xor(cnt, 8);
      cnt += __shfl_xor(cnt, 16);
      bool ge = cnt >= TOPKN;
      lo = ge ? mid : lo;
      hi = ge ? hi : mid;
    }
    if ((lane & 31) == 0) Tlds[r] = lo;
  }
  __syncthreads();
  const unsigned TA = Tlds[c];
  const unsigned TB = Tlds[c + 16];

  // ---- PV: fused exp, 2-stage V prefetch; one V fragment -> two MFMAs ----
  const float C1 = 1.44269504f / 8192.0f;
  const float C2 = -49152.0f * (1.44269504f / 8192.0f);
  f32x4 opvA[4], opvB[4];
#pragma unroll
  for (int j = 0; j < 4; ++j) {
    opvA[j] = (f32x4){0.f, 0.f, 0.f, 0.f};
    opvB[j] = (f32x4){0.f, 0.f, 0.f, 0.f};
  }
  float zA = 0.f, zB = 0.f;
  {
    const unsigned short* vb0 = Vt + ((size_t)bh * DH + c) * SEQ + wid * 128 + g * 4;
    s16x4 va[2][4];
#pragma unroll
    for (int j = 0; j < 4; ++j)
      va[0][j] = *(const s16x4*)(vb0 + (size_t)j * 16 * SEQ);
#pragma unroll
    for (int kt = 0; kt < 8; ++kt) {
      const int cur = kt & 1, nxt = cur ^ 1;
      if (kt < 7) {
#pragma unroll
        for (int j = 0; j < 4; ++j)
          va[nxt][j] = *(const s16x4*)(vb0 + (size_t)j * 16 * SEQ + (kt + 1) * 16);
      }
      unsigned pa0 = pkA[kt][0], pa1 = pkA[kt][1];
      unsigned ua0 = pa0 & 0xFFFFu, ua1 = pa0 >> 16;
      unsigned ua2 = pa1 & 0xFFFFu, ua3 = pa1 >> 16;
      float ea0 = (ua0 >= TA) ? exp2f(fmaf((float)ua0, C1, C2)) : 0.f;
      float ea1 = (ua1 >= TA) ? exp2f(fmaf((float)ua1, C1, C2)) : 0.f;
      float ea2 = (ua2 >= TA) ? exp2f(fmaf((float)ua2, C1, C2)) : 0.f;
      float ea3 = (ua3 >= TA) ? exp2f(fmaf((float)ua3, C1, C2)) : 0.f;
      zA += (ea0 + ea1) + (ea2 + ea3);
      union { s16x4 v; unsigned u[2]; } pbA;
      pbA.u[0] = ((__float_as_uint(ea0) + 0x8000u) >> 16) |
                 ((__float_as_uint(ea1) + 0x8000u) & 0xFFFF0000u);
      pbA.u[1] = ((__float_as_uint(ea2) + 0x8000u) >> 16) |
                 ((__float_as_uint(ea3) + 0x8000u) & 0xFFFF0000u);
      unsigned pb0 = pkB[kt][0], pb1 = pkB[kt][1];
      unsigned ub0 = pb0 & 0xFFFFu, ub1 = pb0 >> 16;
      unsigned ub2 = pb1 & 0xFFFFu, ub3 = pb1 >> 16;
      float eb0 = (ub0 >= TB) ? exp2f(fmaf((float)ub0, C1, C2)) : 0.f;
      float eb1 = (ub1 >= TB) ? exp2f(fmaf((float)ub1, C1, C2)) : 0.f;
      float eb2 = (ub2 >= TB) ? exp2f(fmaf((float)ub2, C1, C2)) : 0.f;
      float eb3 = (ub3 >= TB) ? exp2f(fmaf((float)ub3, C1, C2)) : 0.f;
      zB += (eb0 + eb1) + (eb2 + eb3);
      union { s16x4 v; unsigned u[2]; } pbB;
      pbB.u[0] = ((__float_as_uint(eb0) + 0x8000u) >> 16) |
                 ((__float_as_uint(eb1) + 0x8000u) & 0xFFFF0000u);
      pbB.u[1] = ((__float_as_uint(eb2) + 0x8000u) >> 16) |
                 ((__float_as_uint(eb3) + 0x8000u) & 0xFFFF0000u);
#pragma unroll
      for (int j = 0; j < 4; ++j) {
        MFMA1616(opvA[j], va[cur][j], pbA.v);
        MFMA1616(opvB[j], va[cur][j], pbB.v);
      }
    }
    MFMA1616_FENCE();
  }

  // ---- publish partials (sc region dead) ----
  zA += __shfl_xor(zA, 16);
  zA += __shfl_xor(zA, 32);
  zB += __shfl_xor(zB, 16);
  zB += __shfl_xor(zB, 32);
  if (lane < 16) {
    szum[c][wid] = zA;
    szum[c + 16][wid] = zB;
  }
  __syncthreads();
#pragma unroll
  for (int j = 0; j < 4; ++j) {
    *(f32x4*)&ctxp[wid][c][j * 16 + g * 4] = opvA[j];
    *(f32x4*)&ctxp[wid][c + 16][j * 16 + g * 4] = opvB[j];
  }
  __syncthreads();

  // ---- epilogue: 512 threads, one uint4 output each ----
  if (t < 512) {
    const int q = t >> 4, d4 = t & 15;
    float4 z0 = *(float4*)&szum[q][0];
    float4 z1 = *(float4*)&szum[q][4];
    float4 z2 = *(float4*)&szum[q][8];
    float4 z3 = *(float4*)&szum[q][12];
    float rinv = 1.f / ((z0.x + z0.y + z0.z + z0.w) + (z1.x + z1.y + z1.z + z1.w) +
                        (z2.x + z2.y + z2.z + z2.w) + (z3.x + z3.y + z3.z + z3.w));
    f32x4 ssum = (f32x4){0.f, 0.f, 0.f, 0.f};
#pragma unroll
    for (int w2 = 0; w2 < 16; ++w2)
      ssum += *(const f32x4*)&ctxp[w2][q][d4 * 4];
    unsigned ov[4];
    ov[0] = packHL(ssum[0] * rinv);
    ov[1] = packHL(ssum[1] * rinv);
    ov[2] = packHL(ssum[2] * rinv);
    ov[3] = packHL(ssum[3] * rinv);
    *(uint4*)&CtxP[(rowb + q0 + q) * DM + h * DH + d4 * 4] = *(uint4*)&ov[0];
  }
}

extern "C" void kernel_launch(void* const* d_in, const int* in_sizes, int n_in,
                              void* d_out, int out_size, void* d_ws, size_t ws_size,
                              hipStream_t stream) {
  const float* q  = (const float*)d_in[0];
  const float* k  = (const float*)d_in[1];
  const float* v  = (const float*)d_in[2];
  const float* Wq = (const float*)d_in[3];
  const float* bq = (const float*)d_in[4];
  const float* Wk = (const float*)d_in[5];
  const float* bk = (const float*)d_in[6];
  const float* Wv = (const float*)d_in[7];
  const float* bv = (const float*)d_in[8];
  const float* Wo = (const float*)d_in[9];
  const float* bo = (const float*)d_in[10];
  float* out = (float*)d_out;

  char* ws = (char*)d_ws;
  unsigned* QHL       = (unsigned*)ws;                        // 16 MiB (packed hi|lo)
  unsigned short* Khi = (unsigned short*)(ws + (16u << 20));  // 8 MiB
  unsigned short* Klo = (unsigned short*)(ws + (24u << 20));  // 8 MiB
  unsigned short* Vt  = (unsigned short*)(ws + (32u << 20));  // 8 MiB
  unsigned short* Whi = (unsigned short*)(ws + (40u << 20));  // 2 MiB (reused)
  unsigned short* Wlo = (unsigned short*)(ws + (42u << 20));  // 2 MiB (reused)

  convW<<<1024, 256, 0, stream>>>(Wq, Whi, Wlo);
  gemm_mfma<0, 1><<<256, 512, 0, stream>>>(q, Whi, Wlo, bq, QHL, nullptr);
  convW<<<1024, 256, 0, stream>>>(Wk, Whi, Wlo);
  gemm_mfma<0, 2><<<256, 512, 0, stream>>>(k, Whi, Wlo, bk, Khi, Klo);
  convW<<<1024, 256, 0, stream>>>(Wv, Whi, Wlo);
  gemm_mfma<0, 3><<<256, 512, 0, stream>>>(v, Whi, Wlo, bv, Vt, nullptr);
  attn_mfma<<<BATCH * NH * (SEQ / 32), 1024, 0, stream>>>(QHL, Khi, Klo, Vt, QHL);
  convW<<<1024, 256, 0, stream>>>(Wo, Whi, Wlo);
  gemm_mfma<1, 0><<<256, 512, 0, stream>>>(QHL, Whi, Wlo, bo, out, nullptr);
}

// Round 16
// 602.067 us; speedup vs baseline: 1.0840x; 1.0840x over previous
//
#include <hip/hip_runtime.h>
#include <math.h>

#define BATCH 2
#define SEQ 2048
#define DM 1024
#define NH 16
#define DH 64
#define TOPKN 1024
#define MROWS (BATCH * SEQ)  // 4096

typedef float f32x4 __attribute__((ext_vector_type(4)));
typedef short s16x8 __attribute__((ext_vector_type(8)));
typedef short s16x4 __attribute__((ext_vector_type(4)));

// PV MFMA: 16x16x16 bf16 (B-fragment k-chunk of 4 matches swapped-QK^T acc layout)
#if __has_builtin(__builtin_amdgcn_mfma_f32_16x16x16_bf16)
#define MFMA1616(acc, a, b) acc = __builtin_amdgcn_mfma_f32_16x16x16_bf16(a, b, acc, 0, 0, 0)
#define MFMA1616_FENCE()
#elif __has_builtin(__builtin_amdgcn_mfma_f32_16x16x16bf16_1k)
#define MFMA1616(acc, a, b) acc = __builtin_amdgcn_mfma_f32_16x16x16bf16_1k(a, b, acc, 0, 0, 0)
#define MFMA1616_FENCE()
#else
#define MFMA1616(acc, a, b) \
  asm volatile("v_mfma_f32_16x16x16_bf16 %0, %1, %2, %0" : "+v"(acc) : "v"(a), "v"(b))
#define MFMA1616_FENCE() asm volatile("s_nop 7\ns_nop 7")
#endif

__device__ __forceinline__ unsigned short f2bf(float x) {
  unsigned u = __float_as_uint(x);
  return (unsigned short)((u + 0x7FFFu + ((u >> 16) & 1u)) >> 16);
}
__device__ __forceinline__ unsigned packHL(float x) {
  unsigned h = f2bf(x);
  float r = x - __uint_as_float(h << 16);
  unsigned l = f2bf(r);
  return h | (l << 16);
}
// hi-bf16 pair of two f32 (truncated) -> one u32 via v_perm
__device__ __forceinline__ unsigned hipair(float a, float b) {
  return __builtin_amdgcn_perm(__float_as_uint(b), __float_as_uint(a), 0x07060302u);
}
// lo-residual bf16 pair (RNE) via v_cvt_pk_bf16_f32
__device__ __forceinline__ unsigned lopair(float a, float b) {
  float ra = a - __uint_as_float(__float_as_uint(a) & 0xFFFF0000u);
  float rb = b - __uint_as_float(__float_as_uint(b) & 0xFFFF0000u);
  unsigned out;
  asm("v_cvt_pk_bf16_f32 %0, %1, %2" : "=v"(out) : "v"(ra), "v"(rb));
  return out;
}

// ---------------- W pre-convert: f32 -> hi/lo bf16 slabs ----------------
__global__ __launch_bounds__(256) void convW(const float* __restrict__ W,
                                             unsigned short* __restrict__ Whi,
                                             unsigned short* __restrict__ Wlo) {
  int i = (blockIdx.x * 256 + threadIdx.x) * 4;
  float4 x = *(const float4*)&W[i];
  float xs[4] = {x.x, x.y, x.z, x.w};
  union { s16x4 v; unsigned short s[4]; } hu, lu;
#pragma unroll
  for (int e = 0; e < 4; ++e) {
    unsigned short hb = f2bf(xs[e]);
    hu.s[e] = hb;
    lu.s[e] = f2bf(xs[e] - __uint_as_float((unsigned)hb << 16));
  }
  *(s16x4*)&Whi[i] = hu.v;
  *(s16x4*)&Wlo[i] = lu.v;
}

// ---------------- MFMA GEMM: C[4096,1024] = A @ W^T + bias ----------------
// 3-term split-bf16. BM=128, BN=128, BK=64; 512 thr (8 waves 2x4), wave-tile 64x32.
// ASRC: 0 = f32 A (truncate-hi), 1 = packed u32 (hi|lo<<16).
// MODE: 0 f32 out, 1 packed Q(*1024 == 8192/8), 2 Khi/Klo, 3 Vt transposed.
template <int ASRC, int MODE>
__global__ __launch_bounds__(512) void gemm_mfma(
    const void* __restrict__ Asrc, const unsigned short* __restrict__ Whi,
    const unsigned short* __restrict__ Wlo, const float* __restrict__ bias,
    void* __restrict__ out0, void* __restrict__ out1) {
  __shared__ unsigned short Ah[128][64], Al[128][64];
  __shared__ unsigned short Bh[128][64], Bl[128][64];

  const int f = blockIdx.x;              // 256 blocks
  const int xcd = f & 7, r_ = f >> 3;
  const int bm = xcd * 4 + (r_ >> 3);
  const int bn = r_ & 7;
  const int m0g = bm * 128, n0g = bn * 128;
  const int t = threadIdx.x, w = t >> 6, lane = t & 63;
  const int g = lane >> 4, c = lane & 15;
  const int wm = w >> 2, wn = w & 3;

  f32x4 acc[4][2];
#pragma unroll
  for (int i = 0; i < 4; ++i)
#pragma unroll
    for (int j = 0; j < 2; ++j) acc[i][j] = (f32x4){0.f, 0.f, 0.f, 0.f};

#pragma unroll 1
  for (int k0 = 0; k0 < 1024; k0 += 64) {
#pragma unroll
    for (int i = 0; i < 2; ++i) {
      int oid = t * 2 + i;
      int rr = oid >> 3, j = oid & 7;
      unsigned hw[4], lw[4];
      if (ASRC == 0) {
        const float* src = (const float*)Asrc + (size_t)(m0g + rr) * 1024 + k0 + j * 8;
        float4 x0 = *(const float4*)src, x1 = *(const float4*)(src + 4);
        float xs[8] = {x0.x, x0.y, x0.z, x0.w, x1.x, x1.y, x1.z, x1.w};
#pragma unroll
        for (int p = 0; p < 4; ++p) {
          hw[p] = hipair(xs[2 * p], xs[2 * p + 1]);
          lw[p] = lopair(xs[2 * p], xs[2 * p + 1]);
        }
      } else {
        const unsigned* src = (const unsigned*)Asrc + (size_t)(m0g + rr) * 1024 + k0 + j * 8;
        uint4 u0 = *(const uint4*)src, u1 = *(const uint4*)(src + 4);
        unsigned us[8] = {u0.x, u0.y, u0.z, u0.w, u1.x, u1.y, u1.z, u1.w};
#pragma unroll
        for (int p = 0; p < 4; ++p) {
          hw[p] = __builtin_amdgcn_perm(us[2 * p + 1], us[2 * p], 0x05040100u);
          lw[p] = __builtin_amdgcn_perm(us[2 * p + 1], us[2 * p], 0x07060302u);
        }
      }
      int od = (j ^ (rr & 7)) * 8;
      *(uint4*)&Ah[rr][od] = make_uint4(hw[0], hw[1], hw[2], hw[3]);
      *(uint4*)&Al[rr][od] = make_uint4(lw[0], lw[1], lw[2], lw[3]);
    }
#pragma unroll
    for (int i = 0; i < 4; ++i) {
      int oid = t * 4 + i;
      int pl = oid >> 10, idx = oid & 1023, rr = idx >> 3, j = idx & 7;
      const unsigned short* src = (pl ? Wlo : Whi) + (size_t)(n0g + rr) * 1024 + k0 + j * 8;
      uint4 d = *(const uint4*)src;
      int od = (j ^ (rr & 7)) * 8;
      if (pl) *(uint4*)&Bl[rr][od] = d; else *(uint4*)&Bh[rr][od] = d;
    }
    __syncthreads();
#pragma unroll
    for (int k2 = 0; k2 < 2; ++k2) {
      s16x8 ah[4], al4[4], bh[2], bl[2];
      int ob = ((k2 * 4 + g) ^ (c & 7)) * 8;
#pragma unroll
      for (int i = 0; i < 4; ++i) {
        int rr = wm * 64 + i * 16 + c;
        ah[i] = *(const s16x8*)&Ah[rr][ob];
        al4[i] = *(const s16x8*)&Al[rr][ob];
      }
#pragma unroll
      for (int j = 0; j < 2; ++j) {
        int rr = wn * 32 + j * 16 + c;
        bh[j] = *(const s16x8*)&Bh[rr][ob];
        bl[j] = *(const s16x8*)&Bl[rr][ob];
      }
#pragma unroll
      for (int i = 0; i < 4; ++i)
#pragma unroll
        for (int j = 0; j < 2; ++j) {
          acc[i][j] = __builtin_amdgcn_mfma_f32_16x16x32_bf16(ah[i], bh[j], acc[i][j], 0, 0, 0);
          acc[i][j] = __builtin_amdgcn_mfma_f32_16x16x32_bf16(ah[i], bl[j], acc[i][j], 0, 0, 0);
          acc[i][j] = __builtin_amdgcn_mfma_f32_16x16x32_bf16(al4[i], bh[j], acc[i][j], 0, 0, 0);
        }
    }
    __syncthreads();
  }

#pragma unroll
  for (int j = 0; j < 2; ++j) {
    const int col = n0g + wn * 32 + j * 16 + c;
    const float bj = bias[col];
#pragma unroll
    for (int i = 0; i < 4; ++i) {
      const int row0 = m0g + wm * 64 + i * 16 + g * 4;
      if (MODE == 0) {
        float* O = (float*)out0;
#pragma unroll
        for (int rr = 0; rr < 4; ++rr)
          O[(size_t)(row0 + rr) * 1024 + col] = acc[i][j][rr] + bj;
      } else if (MODE == 1) {
        unsigned* Q = (unsigned*)out0;
#pragma unroll
        for (int rr = 0; rr < 4; ++rr)
          Q[(size_t)(row0 + rr) * 1024 + col] = packHL((acc[i][j][rr] + bj) * 1024.0f);
      } else if (MODE == 2) {
        unsigned short* Khi = (unsigned short*)out0;
        unsigned short* Klo = (unsigned short*)out1;
#pragma unroll
        for (int rr = 0; rr < 4; ++rr) {
          float x = acc[i][j][rr] + bj;
          unsigned short hb = f2bf(x);
          Khi[(size_t)(row0 + rr) * 1024 + col] = hb;
          Klo[(size_t)(row0 + rr) * 1024 + col] = f2bf(x - __uint_as_float((unsigned)hb << 16));
        }
      } else {
        unsigned short* Vt = (unsigned short*)out0;
        int b = row0 >> 11, l0 = row0 & (SEQ - 1);
        int h = col >> 6, dh = col & 63;
        union { s16x4 v; unsigned short sh[4]; } vv;
#pragma unroll
        for (int rr = 0; rr < 4; ++rr) vv.sh[rr] = f2bf(acc[i][j][rr] + bj);
        *(s16x4*)&Vt[(((size_t)b * NH + h) * DH + dh) * SEQ + l0] = vv.v;
      }
    }
  }
}

// ---------------- fused prob-sparse attention (q=32 per WG, 16 waves) ---------
// 2048 WGs x 1024 thr. ROUND-13 STRUCTURE (the measured-best 451 us, exactly at
// the 128 unified-reg envelope of 4 waves/SIMD) with round-15's cheaper
// quantize: Q pre-scaled by 1024 and MFMA acc INIT=32768.5, so the accumulator
// IS the u16 code u = s*8192+32768.5 (quantize = fmin + cvt).
// NO explicit prefetch/double-buffer (r15: +24 regs -> scratch spill, +50 us).
// NO packed-u16 builtins in bisection (r14: scalarized, +40 us).
__global__ __launch_bounds__(1024, 4) void attn_mfma(
    const unsigned* __restrict__ QHL, const unsigned short* __restrict__ Khi,
    const unsigned short* __restrict__ Klo, const unsigned short* __restrict__ Vt,
    unsigned* __restrict__ CtxP) {
  __shared__ __align__(16) char smem[16 * 32 * 66 * 4];
  __shared__ __align__(16) float szum[32][16];
  __shared__ unsigned Tlds[32];
  unsigned (*sc)[1028] = (unsigned(*)[1028])smem;
  float (*ctxp)[32][66] = (float(*)[32][66])smem;

  int wg = blockIdx.x;
  wg = (wg & 7) * 256 + (wg >> 3);                  // XCD-contiguous (2048 = 8*256)
  const int bh = wg >> 6, qt = wg & 63;
  const int b = bh >> 4, h = bh & 15;
  const int q0 = qt * 32;
  const int t = threadIdx.x, wid = t >> 6, lane = t & 63;
  const int g = lane >> 4, c = lane & 15;
  const size_t rowb = (size_t)b * SEQ;

  // ---- Q B-fragments for both q-halves (packed u32, pre-scaled by 1024) ----
  s16x8 qhiA[2], qloA[2], qhiB[2], qloB[2];
#pragma unroll
  for (int qh = 0; qh < 2; ++qh) {
    const unsigned* qp = QHL + (rowb + q0 + qh * 16 + c) * DM + h * DH + g * 8;
#pragma unroll
    for (int ds = 0; ds < 2; ++ds) {
      unsigned uw[8];
      *(uint4*)&uw[0] = *(const uint4*)(qp + ds * 32);
      *(uint4*)&uw[4] = *(const uint4*)(qp + ds * 32 + 4);
      union { s16x8 v; unsigned u[4]; } hi_, lo_;
#pragma unroll
      for (int p = 0; p < 4; ++p) {
        hi_.u[p] = (uw[2 * p] & 0xFFFFu) | (uw[2 * p + 1] << 16);
        lo_.u[p] = (uw[2 * p] >> 16) | (uw[2 * p + 1] & 0xFFFF0000u);
      }
      if (qh == 0) { qhiA[ds] = hi_.v; qloA[ds] = lo_.v; }
      else         { qhiB[ds] = hi_.v; qloB[ds] = lo_.v; }
    }
  }

  // ---- swapped QK^T, dual q-halves; acc init carries the +32768.5 offset ----
  unsigned pkA[8][2], pkB[8][2];
  {
    const f32x4 INIT = (f32x4){32768.5f, 32768.5f, 32768.5f, 32768.5f};
    const size_t kcol = (size_t)h * DH + g * 8;
#pragma unroll
    for (int tt = 0; tt < 8; ++tt) {
      const size_t krow = (rowb + wid * 128 + tt * 16 + c) * DM + kcol;
      s16x8 kh0 = *(const s16x8*)(Khi + krow);
      s16x8 kh1 = *(const s16x8*)(Khi + krow + 32);
      s16x8 kl0 = *(const s16x8*)(Klo + krow);
      s16x8 kl1 = *(const s16x8*)(Klo + krow + 32);
      f32x4 aA = __builtin_amdgcn_mfma_f32_16x16x32_bf16(kh0, qhiA[0], INIT, 0, 0, 0);
      f32x4 aB = __builtin_amdgcn_mfma_f32_16x16x32_bf16(kh0, qhiB[0], INIT, 0, 0, 0);
      aA = __builtin_amdgcn_mfma_f32_16x16x32_bf16(kh1, qhiA[1], aA, 0, 0, 0);
      aB = __builtin_amdgcn_mfma_f32_16x16x32_bf16(kh1, qhiB[1], aB, 0, 0, 0);
      aA = __builtin_amdgcn_mfma_f32_16x16x32_bf16(kl0, qhiA[0], aA, 0, 0, 0);
      aB = __builtin_amdgcn_mfma_f32_16x16x32_bf16(kl0, qhiB[0], aB, 0, 0, 0);
      aA = __builtin_amdgcn_mfma_f32_16x16x32_bf16(kl1, qhiA[1], aA, 0, 0, 0);
      aB = __builtin_amdgcn_mfma_f32_16x16x32_bf16(kl1, qhiB[1], aB, 0, 0, 0);
      aA = __builtin_amdgcn_mfma_f32_16x16x32_bf16(kh0, qloA[0], aA, 0, 0, 0);
      aB = __builtin_amdgcn_mfma_f32_16x16x32_bf16(kh0, qloB[0], aB, 0, 0, 0);
      aA = __builtin_amdgcn_mfma_f32_16x16x32_bf16(kh1, qloA[1], aA, 0, 0, 0);
      aB = __builtin_amdgcn_mfma_f32_16x16x32_bf16(kh1, qloB[1], aB, 0, 0, 0);
      unsigned a0 = (unsigned)fminf(aA[0], 65535.f);
      unsigned a1 = (unsigned)fminf(aA[1], 65535.f);
      unsigned a2 = (unsigned)fminf(aA[2], 65535.f);
      unsigned a3 = (unsigned)fminf(aA[3], 65535.f);
      pkA[tt][0] = a0 | (a1 << 16);
      pkA[tt][1] = a2 | (a3 << 16);
      unsigned b0 = (unsigned)fminf(aB[0], 65535.f);
      unsigned b1 = (unsigned)fminf(aB[1], 65535.f);
      unsigned b2 = (unsigned)fminf(aB[2], 65535.f);
      unsigned b3 = (unsigned)fminf(aB[3], 65535.f);
      pkB[tt][0] = b0 | (b1 << 16);
      pkB[tt][1] = b2 | (b3 << 16);
    }
  }

  // ---- S1: publish score tile ----
#pragma unroll
  for (int tt = 0; tt < 8; ++tt) {
    int col = wid * 64 + tt * 8 + g * 2;
    *(uint2*)&sc[c][col] = make_uint2(pkA[tt][0], pkA[tt][1]);
    *(uint2*)&sc[c + 16][col] = make_uint2(pkB[tt][0], pkB[tt][1]);
  }
  __syncthreads();

  // ---- S2: wave-local exact selection (explicit compares) ----
  {
    const int r = 2 * wid + (lane >> 5);
    const int hl = lane & 31;
    uint4 ts[8];
#pragma unroll
    for (int i = 0; i < 8; ++i)
      ts[i] = *(const uint4*)&sc[r][hl * 4 + i * 128];

    unsigned lo = 30720u, hi = 34816u;
#pragma unroll 1
    for (int it = 0; it < 12; ++it) {
      const unsigned mid = (lo + hi) >> 1;
      int cnt = 0;
#pragma unroll
      for (int i = 0; i < 8; ++i) {
        unsigned a0 = ts[i].x, a1 = ts[i].y, a2 = ts[i].z, a3 = ts[i].w;
        cnt += ((a0 & 0xFFFFu) >= mid) ? 1 : 0;
        cnt += ((a0 >> 16) >= mid) ? 1 : 0;
        cnt += ((a1 & 0xFFFFu) >= mid) ? 1 : 0;
        cnt += ((a1 >> 16) >= mid) ? 1 : 0;
        cnt += ((a2 & 0xFFFFu) >= mid) ? 1 : 0;
        cnt += ((a2 >> 16) >= mid) ? 1 : 0;
        cnt += ((a3 & 0xFFFFu) >= mid) ? 1 : 0;
        cnt += ((a3 >> 16) >= mid) ? 1 : 0;
      }
      cnt += __shfl_xor(cnt, 1);
      cnt += __shfl_xor(cnt, 2);
      cnt += __shfl_xor(cnt, 4);
      cnt += __shfl_xor(cnt, 8);
      cnt += __shfl_xor(cnt, 16);
      bool ge = cnt >= TOPKN;
      lo = ge ? mid : lo;
      hi = ge ? hi : mid;
    }
    if ((lane & 31) == 0) Tlds[r] = lo;
  }
  __syncthreads();
  const unsigned TA = Tlds[c];
  const unsigned TB = Tlds[c + 16];

  // ---- PV: fused exp; one V fragment drives both q-half MFMAs ----
  const float C1 = 1.44269504f / 8192.0f;
  const float C2 = -49152.0f * (1.44269504f / 8192.0f);
  f32x4 opvA[4], opvB[4];
#pragma unroll
  for (int j = 0; j < 4; ++j) {
    opvA[j] = (f32x4){0.f, 0.f, 0.f, 0.f};
    opvB[j] = (f32x4){0.f, 0.f, 0.f, 0.f};
  }
  float zA = 0.f, zB = 0.f;
  {
    const unsigned short* vb0 = Vt + ((size_t)bh * DH + c) * SEQ + wid * 128 + g * 4;
#pragma unroll
    for (int kt = 0; kt < 8; ++kt) {
      unsigned pa0 = pkA[kt][0], pa1 = pkA[kt][1];
      unsigned ua0 = pa0 & 0xFFFFu, ua1 = pa0 >> 16;
      unsigned ua2 = pa1 & 0xFFFFu, ua3 = pa1 >> 16;
      float ea0 = (ua0 >= TA) ? exp2f(fmaf((float)ua0, C1, C2)) : 0.f;
      float ea1 = (ua1 >= TA) ? exp2f(fmaf((float)ua1, C1, C2)) : 0.f;
      float ea2 = (ua2 >= TA) ? exp2f(fmaf((float)ua2, C1, C2)) : 0.f;
      float ea3 = (ua3 >= TA) ? exp2f(fmaf((float)ua3, C1, C2)) : 0.f;
      zA += (ea0 + ea1) + (ea2 + ea3);
      union { s16x4 v; unsigned u[2]; } pbA;
      pbA.u[0] = ((__float_as_uint(ea0) + 0x8000u) >> 16) |
                 ((__float_as_uint(ea1) + 0x8000u) & 0xFFFF0000u);
      pbA.u[1] = ((__float_as_uint(ea2) + 0x8000u) >> 16) |
                 ((__float_as_uint(ea3) + 0x8000u) & 0xFFFF0000u);
      unsigned pb0 = pkB[kt][0], pb1 = pkB[kt][1];
      unsigned ub0 = pb0 & 0xFFFFu, ub1 = pb0 >> 16;
      unsigned ub2 = pb1 & 0xFFFFu, ub3 = pb1 >> 16;
      float eb0 = (ub0 >= TB) ? exp2f(fmaf((float)ub0, C1, C2)) : 0.f;
      float eb1 = (ub1 >= TB) ? exp2f(fmaf((float)ub1, C1, C2)) : 0.f;
      float eb2 = (ub2 >= TB) ? exp2f(fmaf((float)ub2, C1, C2)) : 0.f;
      float eb3 = (ub3 >= TB) ? exp2f(fmaf((float)ub3, C1, C2)) : 0.f;
      zB += (eb0 + eb1) + (eb2 + eb3);
      union { s16x4 v; unsigned u[2]; } pbB;
      pbB.u[0] = ((__float_as_uint(eb0) + 0x8000u) >> 16) |
                 ((__float_as_uint(eb1) + 0x8000u) & 0xFFFF0000u);
      pbB.u[1] = ((__float_as_uint(eb2) + 0x8000u) >> 16) |
                 ((__float_as_uint(eb3) + 0x8000u) & 0xFFFF0000u);
#pragma unroll
      for (int j = 0; j < 4; ++j) {
        s16x4 va = *(const s16x4*)(vb0 + (size_t)j * 16 * SEQ + kt * 16);
        MFMA1616(opvA[j], va, pbA.v);
        MFMA1616(opvB[j], va, pbB.v);
      }
    }
    MFMA1616_FENCE();
  }

  // ---- publish partials (sc region dead) ----
  zA += __shfl_xor(zA, 16);
  zA += __shfl_xor(zA, 32);
  zB += __shfl_xor(zB, 16);
  zB += __shfl_xor(zB, 32);
  if (lane < 16) {
    szum[c][wid] = zA;
    szum[c + 16][wid] = zB;
  }
  __syncthreads();
#pragma unroll
  for (int j = 0; j < 4; ++j) {
    *(f32x4*)&ctxp[wid][c][j * 16 + g * 4] = opvA[j];
    *(f32x4*)&ctxp[wid][c + 16][j * 16 + g * 4] = opvB[j];
  }
  __syncthreads();

  // ---- epilogue: 512 threads, one uint4 output each ----
  if (t < 512) {
    const int q = t >> 4, d4 = t & 15;
    float4 z0 = *(float4*)&szum[q][0];
    float4 z1 = *(float4*)&szum[q][4];
    float4 z2 = *(float4*)&szum[q][8];
    float4 z3 = *(float4*)&szum[q][12];
    float rinv = 1.f / ((z0.x + z0.y + z0.z + z0.w) + (z1.x + z1.y + z1.z + z1.w) +
                        (z2.x + z2.y + z2.z + z2.w) + (z3.x + z3.y + z3.z + z3.w));
    f32x4 ssum = (f32x4){0.f, 0.f, 0.f, 0.f};
#pragma unroll
    for (int w2 = 0; w2 < 16; ++w2)
      ssum += *(const f32x4*)&ctxp[w2][q][d4 * 4];
    unsigned ov[4];
    ov[0] = packHL(ssum[0] * rinv);
    ov[1] = packHL(ssum[1] * rinv);
    ov[2] = packHL(ssum[2] * rinv);
    ov[3] = packHL(ssum[3] * rinv);
    *(uint4*)&CtxP[(rowb + q0 + q) * DM + h * DH + d4 * 4] = *(uint4*)&ov[0];
  }
}

extern "C" void kernel_launch(void* const* d_in, const int* in_sizes, int n_in,
                              void* d_out, int out_size, void* d_ws, size_t ws_size,
                              hipStream_t stream) {
  const float* q  = (const float*)d_in[0];
  const float* k  = (const float*)d_in[1];
  const float* v  = (const float*)d_in[2];
  const float* Wq = (const float*)d_in[3];
  const float* bq = (const float*)d_in[4];
  const float* Wk = (const float*)d_in[5];
  const float* bk = (const float*)d_in[6];
  const float* Wv = (const float*)d_in[7];
  const float* bv = (const float*)d_in[8];
  const float* Wo = (const float*)d_in[9];
  const float* bo = (const float*)d_in[10];
  float* out = (float*)d_out;

  char* ws = (char*)d_ws;
  unsigned* QHL       = (unsigned*)ws;                        // 16 MiB (packed hi|lo)
  unsigned short* Khi = (unsigned short*)(ws + (16u << 20));  // 8 MiB
  unsigned short* Klo = (unsigned short*)(ws + (24u << 20));  // 8 MiB
  unsigned short* Vt  = (unsigned short*)(ws + (32u << 20));  // 8 MiB
  unsigned short* Whi = (unsigned short*)(ws + (40u << 20));  // 2 MiB (reused)
  unsigned short* Wlo = (unsigned short*)(ws + (42u << 20));  // 2 MiB (reused)

  convW<<<1024, 256, 0, stream>>>(Wq, Whi, Wlo);
  gemm_mfma<0, 1><<<256, 512, 0, stream>>>(q, Whi, Wlo, bq, QHL, nullptr);
  convW<<<1024, 256, 0, stream>>>(Wk, Whi, Wlo);
  gemm_mfma<0, 2><<<256, 512, 0, stream>>>(k, Whi, Wlo, bk, Khi, Klo);
  convW<<<1024, 256, 0, stream>>>(Wv, Whi, Wlo);
  gemm_mfma<0, 3><<<256, 512, 0, stream>>>(v, Whi, Wlo, bv, Vt, nullptr);
  attn_mfma<<<BATCH * NH * (SEQ / 32), 1024, 0, stream>>>(QHL, Khi, Klo, Vt, QHL);
  convW<<<1024, 256, 0, stream>>>(Wo, Whi, Wlo);
  gemm_mfma<1, 0><<<256, 512, 0, stream>>>(QHL, Whi, Wlo, bo, out, nullptr);
}